// Round 1
// baseline (25469.101 us; speedup 1.0000x reference)
//
#include <hip/hip_runtime.h>

// Problem dims (fixed)
constexpr int T  = 512;
constexpr int NB = 64;    // batch
constexpr int NI = 128;   // input
constexpr int NH = 512;   // hidden
constexpr int NO = 64;    // output

constexpr float ALPHA = 0.2f;
constexpr float NSC   = 0.063245553203367586f; // 0.1*sqrt(2*ALPHA)

// ---------------------------------------------------------------------------
// flags init (per-launch, so graph replays are deterministic)
__global__ void k_init_flags(int* flags) { flags[threadIdx.x] = 0; }

// ---------------------------------------------------------------------------
// Generic fp32 GEMM: C[M,N] = A[M,K] @ B[N,K]^T + bias[N]
// 64x64 tile, 256 threads, K chunked by 32, LDS stored transposed [k][row].
__global__ __launch_bounds__(256) void k_gemm_nt_bias(
    const float* __restrict__ A, const float* __restrict__ Bm,
    const float* __restrict__ bias, float* __restrict__ C,
    int M, int N, int K)
{
    __shared__ __align__(16) float As[32][68];
    __shared__ __align__(16) float Bs[32][68];
    const int tid = threadIdx.x;
    const int tx = tid & 15, ty = tid >> 4;
    const long row0 = (long)blockIdx.x * 64;
    const long col0 = (long)blockIdx.y * 64;
    const int lr = tid >> 3;   // 0..31
    const int lq = tid & 7;    // 0..7 (16B quad within 32-k chunk)

    float acc[4][4] = {};

    for (int kt = 0; kt < K; kt += 32) {
        #pragma unroll
        for (int hh = 0; hh < 2; ++hh) {
            const int r = lr + hh * 32;
            const float4 va = *(const float4*)&A[(size_t)(row0 + r) * K + kt + lq * 4];
            As[lq*4+0][r] = va.x; As[lq*4+1][r] = va.y;
            As[lq*4+2][r] = va.z; As[lq*4+3][r] = va.w;
            const float4 vb = *(const float4*)&Bm[(size_t)(col0 + r) * K + kt + lq * 4];
            Bs[lq*4+0][r] = vb.x; Bs[lq*4+1][r] = vb.y;
            Bs[lq*4+2][r] = vb.z; Bs[lq*4+3][r] = vb.w;
        }
        __syncthreads();
        #pragma unroll
        for (int kk = 0; kk < 32; ++kk) {
            const float4 a4 = *(const float4*)&As[kk][ty * 4];
            const float4 b4 = *(const float4*)&Bs[kk][tx * 4];
            const float a[4] = {a4.x, a4.y, a4.z, a4.w};
            const float b[4] = {b4.x, b4.y, b4.z, b4.w};
            #pragma unroll
            for (int i = 0; i < 4; ++i)
                #pragma unroll
                for (int j = 0; j < 4; ++j)
                    acc[i][j] += a[i] * b[j];
        }
        __syncthreads();
    }

    #pragma unroll
    for (int i = 0; i < 4; ++i) {
        const long r = row0 + ty * 4 + i;
        const int  cc = (int)col0 + tx * 4;
        float4 ov;
        ov.x = acc[i][0] + bias[cc + 0];
        ov.y = acc[i][1] + bias[cc + 1];
        ov.z = acc[i][2] + bias[cc + 2];
        ov.w = acc[i][3] + bias[cc + 3];
        *(float4*)&C[(size_t)r * N + cc] = ov;
    }
}

// ---------------------------------------------------------------------------
// Recurrent kernel. 256 WGs = 32 groups x 8 members.
//  group g: batches {2g, 2g+1}; member m: hidden cols [64m, 64m+64).
//  blockIdx = m*32 + g  -> a group's members share bid%8 (same XCD, perf only).
// Thread map (512 thr = 8 waves): wave w -> (bl = w>>2, c = w&3), lane l = jj.
//  Lane owns W_rec[64m+l][128c..128c+128) in 32 float4 registers.
//  h lives in LDS; dot-phase h reads are wave-uniform (broadcast, no conflicts).
// Per-step inter-WG exchange: double-buffered ex[2][B][H] in ws + monotonic
//  flags[32][8], agent-scope release/acquire.
__global__ __launch_bounds__(512, 2) void k_rnn(
    const float* __restrict__ W_rec,   // [H][H]
    const float* __restrict__ noise,   // [T][B][H]
    float* __restrict__ rnn,           // [T][B][H]: holds xin(+b_rec) on entry, h on exit
    float* __restrict__ ex,            // [2][B][H]
    int* __restrict__ flags)           // [32][8]
{
    const int bid = blockIdx.x;
    const int g = bid & 31;
    const int m = bid >> 5;
    const int tid = threadIdx.x;
    const int w = tid >> 6;        // wave 0..7
    const int l = tid & 63;        // lane
    const int c  = w & 3;          // k-chunk (128 wide)
    const int bl = w >> 2;         // batch-local 0..1
    const int jdot = m * 64 + l;   // W row this lane owns

    __shared__ __align__(16) float hl[2][NH];   // current h for both batches
    __shared__ float pr[4][132];                // chunk partials (padded)

    // ---- load W chunk into registers (one-time) ----
    float4 wreg[32];
    {
        const float* wp = W_rec + (size_t)jdot * NH + c * 128;
        #pragma unroll
        for (int i = 0; i < 32; ++i) wreg[i] = *(const float4*)(wp + i * 4);
    }

    // epilogue mapping (tid < 128 drives one (b,j) output)
    const int ble = tid >> 6;            // 0..1
    const int jle = tid & 63;
    const int je  = m * 64 + jle;
    const int bge = g * 2 + ble;

    // zero h state
    ((float*)hl)[tid] = 0.f;
    ((float*)hl)[tid + 512] = 0.f;

    // prefetch t=0 xin/noise
    float xin_pf = 0.f, noi_pf = 0.f;
    if (tid < 128) {
        xin_pf = rnn[(size_t)bge * NH + je];
        noi_pf = noise[(size_t)bge * NH + je];
    }
    __syncthreads();

    const int fbase = g * 8;

    for (int t = 0; t < T; ++t) {
        // ---- dot phase: partial = sum over this lane's 128-k chunk ----
        float ax = 0.f, ay = 0.f, az = 0.f, aw = 0.f;
        {
            const float* hp = &hl[bl][c * 128];
            #pragma unroll
            for (int i = 0; i < 32; ++i) {
                const float4 h4 = *(const float4*)(hp + i * 4);  // wave-uniform bcast
                ax += wreg[i].x * h4.x;
                ay += wreg[i].y * h4.y;
                az += wreg[i].z * h4.z;
                aw += wreg[i].w * h4.w;
            }
        }
        pr[c][bl * 64 + l] = (ax + ay) + (az + aw);
        __syncthreads();

        // ---- epilogue: reduce chunks, state update, publish ----
        if (tid < 128) {
            const int oe = tid;
            const float sum = pr[0][oe] + pr[1][oe] + pr[2][oe] + pr[3][oe];
            const float val = xin_pf + sum;                 // b_rec folded into xin
            const float hn  = fmaxf(val, 0.f);
            const float hold = hl[ble][je];
            const float hnew = (1.f - ALPHA) * hold + ALPHA * hn + NSC * noi_pf;
            hl[ble][je] = hnew;
            rnn[((size_t)t * NB + bge) * NH + je] = hnew;    // overwrite xin in place
            ex[((size_t)(t & 1) * NB + bge) * NH + je] = hnew;
            // prefetch next step (t+1 slot still holds xin for our slice)
            const int tn = (t + 1 < T) ? (t + 1) : t;
            xin_pf = rnn[((size_t)tn * NB + bge) * NH + je];
            noi_pf = noise[((size_t)tn * NB + bge) * NH + je];
        }
        __threadfence();
        __syncthreads();
        if (tid == 0)
            __hip_atomic_store(&flags[fbase + m], t + 1,
                               __ATOMIC_RELEASE, __HIP_MEMORY_SCOPE_AGENT);

        // ---- gather peer slices (wave w handles peer w) ----
        if (w != m) {
            int spins = 0;
            while (__hip_atomic_load(&flags[fbase + w],
                                     __ATOMIC_ACQUIRE, __HIP_MEMORY_SCOPE_AGENT) < t + 1) {
                __builtin_amdgcn_s_sleep(1);
                if (++spins > (1 << 24)) break;   // fail loudly, never hang
            }
            const int jg = w * 64 + l;
            #pragma unroll
            for (int b2 = 0; b2 < 2; ++b2)
                hl[b2][jg] = ex[((size_t)(t & 1) * NB + (g * 2 + b2)) * NH + jg];
        }
        __syncthreads();
    }
}

// ---------------------------------------------------------------------------
extern "C" void kernel_launch(void* const* d_in, const int* in_sizes, int n_in,
                              void* d_out, int out_size, void* d_ws, size_t ws_size,
                              hipStream_t stream)
{
    (void)in_sizes; (void)n_in; (void)out_size; (void)ws_size;
    const float* x     = (const float*)d_in[0];
    const float* noise = (const float*)d_in[1];
    const float* W_in  = (const float*)d_in[2];
    const float* W_rec = (const float*)d_in[3];
    const float* b_rec = (const float*)d_in[4];
    const float* W_out = (const float*)d_in[5];
    const float* b_out = (const float*)d_in[6];

    float* out = (float*)d_out;                       // [T*B][O]
    float* rnn = out + (size_t)T * NB * NO;           // [T*B][H] (second output)

    int*   flags = (int*)d_ws;                        // 256 ints
    float* ex    = (float*)((char*)d_ws + 4096);      // 2*B*H floats = 256 KB

    hipLaunchKernelGGL(k_init_flags, dim3(1), dim3(256), 0, stream, flags);

    // xin = x @ W_in^T + b_rec  -> written into rnn region (in-place consumed)
    hipLaunchKernelGGL(k_gemm_nt_bias, dim3((T * NB) / 64, NH / 64), dim3(256), 0, stream,
                       x, W_in, b_rec, rnn, T * NB, NH, NI);

    // sequential recurrence (persistent, flag-synced)
    hipLaunchKernelGGL(k_rnn, dim3(256), dim3(512), 0, stream,
                       W_rec, noise, rnn, ex, flags);

    // output = rnn @ W_out^T + b_out
    hipLaunchKernelGGL(k_gemm_nt_bias, dim3((T * NB) / 64, NO / 64), dim3(256), 0, stream,
                       rnn, W_out, b_out, out, T * NB, NO, NH);
}

// Round 3
// 976.496 us; speedup vs baseline: 26.0821x; 26.0821x over previous
//
#include <hip/hip_runtime.h>

// Problem dims (fixed)
constexpr int T  = 512;
constexpr int NB = 64;    // batch
constexpr int NI = 128;   // input
constexpr int NH = 512;   // hidden
constexpr int NO = 64;    // output

constexpr float ALPHA = 0.2f;
constexpr float NSC   = 0.063245553203367586f; // 0.1*sqrt(2*ALPHA)

// ---------------------------------------------------------------------------
// Generic fp32 GEMM: C[M,N] = A[M,K] @ B[N,K]^T + bias[N]
// 64x64 tile, 256 threads, K chunked by 32, LDS stored transposed [k][row].
__global__ __launch_bounds__(256) void k_gemm_nt_bias(
    const float* __restrict__ A, const float* __restrict__ Bm,
    const float* __restrict__ bias, float* __restrict__ C,
    int M, int N, int K)
{
    __shared__ __align__(16) float As[32][68];
    __shared__ __align__(16) float Bs[32][68];
    const int tid = threadIdx.x;
    const int tx = tid & 15, ty = tid >> 4;
    const long row0 = (long)blockIdx.x * 64;
    const long col0 = (long)blockIdx.y * 64;
    const int lr = tid >> 3;   // 0..31
    const int lq = tid & 7;    // 0..7 (16B quad within 32-k chunk)

    float acc[4][4] = {};

    for (int kt = 0; kt < K; kt += 32) {
        #pragma unroll
        for (int hh = 0; hh < 2; ++hh) {
            const int r = lr + hh * 32;
            const float4 va = *(const float4*)&A[(size_t)(row0 + r) * K + kt + lq * 4];
            As[lq*4+0][r] = va.x; As[lq*4+1][r] = va.y;
            As[lq*4+2][r] = va.z; As[lq*4+3][r] = va.w;
            const float4 vb = *(const float4*)&Bm[(size_t)(col0 + r) * K + kt + lq * 4];
            Bs[lq*4+0][r] = vb.x; Bs[lq*4+1][r] = vb.y;
            Bs[lq*4+2][r] = vb.z; Bs[lq*4+3][r] = vb.w;
        }
        __syncthreads();
        #pragma unroll
        for (int kk = 0; kk < 32; ++kk) {
            const float4 a4 = *(const float4*)&As[kk][ty * 4];
            const float4 b4 = *(const float4*)&Bs[kk][tx * 4];
            const float a[4] = {a4.x, a4.y, a4.z, a4.w};
            const float b[4] = {b4.x, b4.y, b4.z, b4.w};
            #pragma unroll
            for (int i = 0; i < 4; ++i)
                #pragma unroll
                for (int j = 0; j < 4; ++j)
                    acc[i][j] += a[i] * b[j];
        }
        __syncthreads();
    }

    #pragma unroll
    for (int i = 0; i < 4; ++i) {
        const long r = row0 + ty * 4 + i;
        const int  cc = (int)col0 + tx * 4;
        float4 ov;
        ov.x = acc[i][0] + bias[cc + 0];
        ov.y = acc[i][1] + bias[cc + 1];
        ov.z = acc[i][2] + bias[cc + 2];
        ov.w = acc[i][3] + bias[cc + 3];
        *(float4*)&C[(size_t)r * N + cc] = ov;
    }
}

// ---------------------------------------------------------------------------
// Tagged exchange word: high 16 bits = bf16(h), low 16 bits = step tag (t+1).
// Published AND polled with atomic RMWs (relaxed, agent scope): RMWs execute
// at the device coherence point (same mechanism as cross-XCD atomicAdd),
// so visibility cannot be defeated by per-XCD L2 / per-CU L0 caching, and
// no cache-maintenance instructions (buffer_inv/wbl2) appear in the loop.
__device__ __forceinline__ uint32_t pack_h(float h, uint32_t tag) {
    uint32_t u = __float_as_uint(h);
    uint32_t r = (u + 0x7FFFu + ((u >> 16) & 1u)) & 0xFFFF0000u;  // RNE to bf16
    return r | tag;
}

// ---------------------------------------------------------------------------
// Recurrent kernel. 256 WGs = 64 groups (1 batch each) x 4 members.
//  bid = m*64 + b  -> members of group b at bids {b, b+64, b+128, b+192}:
//  all == b (mod 8), so heuristically same XCD (perf only, not correctness).
//  member m owns hidden cols [128m, 128m+128); W slice register-resident
//  (128 floats/lane across 512 threads = 256 KB/WG).
// Thread map: jl = tid&127 (local col), kc = tid>>7 (128-wide k-chunk).
//  Wave-uniform kc -> h reads from LDS are broadcasts (conflict-free).
// Per step: dot -> barrier -> {tid<128: epilogue+publish | tid>=128: poll
//  peers' tagged words} -> barrier. 2-slot exchange buffer; the chain
//  publish(t+3) <- pass-barrier(t+1) <- gather(t+1) <- publish(t+2)
//  <- pass-barrier(t) <- gather(t) guarantees slot words for step t are
//  never overwritten before every consumer of step t has read them.
// Hang-proofing: spin cap 2^14 + sticky 'alive' -> a visibility failure
//  degrades to a fast wrong-answer, never a hung GPU.
__global__ __launch_bounds__(512, 2) void k_rnn(
    const float* __restrict__ W_rec,   // [H][H]
    const float* __restrict__ noise,   // [T][B][H]
    float* __restrict__ rnn,           // [T][B][H]: xin(+b_rec) on entry, h on exit
    uint32_t* __restrict__ ex)         // [2][B][H] tagged words
{
    const int bid = blockIdx.x;
    const int b = bid & 63;        // batch / group
    const int m = bid >> 6;        // member 0..3
    const int tid = threadIdx.x;
    const int jl  = tid & 127;     // local col
    const int kc  = tid >> 7;      // k-chunk 0..3

    __shared__ __align__(16) float hl[NH];      // full h for this batch
    __shared__ float pr[4][128];                // per-chunk partials

    // ---- W slice into registers (one-time): row m*128+jl, k in [128kc,..) ----
    float4 wreg[32];
    {
        const float* wp = W_rec + (size_t)(m * 128 + jl) * NH + kc * 128;
        #pragma unroll
        for (int i = 0; i < 32; ++i) wreg[i] = *(const float4*)(wp + i * 4);
    }

    // epilogue mapping (tid < 128 -> one output col)
    const int gjE = m * 128 + tid;           // valid when tid < 128

    // gather mapping (tid >= 128 -> one peer word)
    const int idx = tid - 128;               // 0..383
    const int pi  = idx >> 7;                // 0..2
    const int mm  = pi + (pi >= m ? 1 : 0);  // peer member
    const int gjG = mm * 128 + (idx & 127);

    // zero h state
    hl[tid] = 0.f;

    // prefetch t=0 xin/noise for own cols
    float xin_pf = 0.f, noi_pf = 0.f;
    if (tid < 128) {
        xin_pf = rnn[(size_t)b * NH + gjE];
        noi_pf = noise[(size_t)b * NH + gjE];
    }
    __syncthreads();

    int alive = 1;   // sticky: once a poll times out, never poll again

    for (int t = 0; t < T; ++t) {
        // ---- dot: partial over this lane's 128-k chunk (h reads broadcast) ----
        float ax = 0.f, ay = 0.f, az = 0.f, aw = 0.f;
        {
            const float* hp = &hl[kc * 128];
            #pragma unroll
            for (int i = 0; i < 32; ++i) {
                const float4 h4 = *(const float4*)(hp + i * 4);
                ax += wreg[i].x * h4.x;
                ay += wreg[i].y * h4.y;
                az += wreg[i].z * h4.z;
                aw += wreg[i].w * h4.w;
            }
        }
        pr[kc][jl] = (ax + ay) + (az + aw);
        __syncthreads();

        const uint32_t want = (uint32_t)(t + 1);
        uint32_t* exslot = ex + ((size_t)(t & 1) * NB + b) * NH;

        if (tid < 128) {
            // ---- epilogue: reduce, state update, publish own slice ----
            const float sum = pr[0][tid] + pr[1][tid] + pr[2][tid] + pr[3][tid];
            const float hn  = fmaxf(xin_pf + sum, 0.f);     // b_rec folded into xin
            const float hnew = (1.f - ALPHA) * hl[gjE] + ALPHA * hn + NSC * noi_pf;
            hl[gjE] = hnew;
            (void)__hip_atomic_exchange(&exslot[gjE], pack_h(hnew, want),
                                        __ATOMIC_RELAXED, __HIP_MEMORY_SCOPE_AGENT);
            rnn[((size_t)t * NB + b) * NH + gjE] = hnew;
            // prefetch next step (t+1 slot still holds xin for our cols)
            const int tn = (t + 1 < T) ? (t + 1) : t;
            xin_pf = rnn[((size_t)tn * NB + b) * NH + gjE];
            noi_pf = noise[((size_t)tn * NB + b) * NH + gjE];
        } else {
            // ---- gather: poll one peer word via RMW (384 threads, 1 each) ----
            uint32_t w;
            if (alive) {
                int spins = 0;
                for (;;) {
                    w = __hip_atomic_fetch_or(&exslot[gjG], 0u,
                                              __ATOMIC_RELAXED, __HIP_MEMORY_SCOPE_AGENT);
                    if ((w & 0xFFFFu) == want) break;
                    __builtin_amdgcn_s_sleep(2);
                    if (++spins > (1 << 14)) { alive = 0; break; }  // fail loudly
                }
            } else {
                w = __hip_atomic_fetch_or(&exslot[gjG], 0u,
                                          __ATOMIC_RELAXED, __HIP_MEMORY_SCOPE_AGENT);
            }
            hl[gjG] = __uint_as_float(w & 0xFFFF0000u);
        }
        __syncthreads();
    }
}

// ---------------------------------------------------------------------------
extern "C" void kernel_launch(void* const* d_in, const int* in_sizes, int n_in,
                              void* d_out, int out_size, void* d_ws, size_t ws_size,
                              hipStream_t stream)
{
    (void)in_sizes; (void)n_in; (void)out_size; (void)ws_size;
    const float* x     = (const float*)d_in[0];
    const float* noise = (const float*)d_in[1];
    const float* W_in  = (const float*)d_in[2];
    const float* W_rec = (const float*)d_in[3];
    const float* b_rec = (const float*)d_in[4];
    const float* W_out = (const float*)d_in[5];
    const float* b_out = (const float*)d_in[6];

    float* out = (float*)d_out;                       // [T*B][O]
    float* rnn = out + (size_t)T * NB * NO;           // [T*B][H] (second output)

    uint32_t* ex = (uint32_t*)d_ws;                   // [2][B][H] = 256 KB

    // clear exchange tags (replay-deterministic; 0 never matches a wanted tag)
    hipMemsetAsync(ex, 0, (size_t)2 * NB * NH * sizeof(uint32_t), stream);

    // xin = x @ W_in^T + b_rec  -> written into rnn region (in-place consumed)
    hipLaunchKernelGGL(k_gemm_nt_bias, dim3((T * NB) / 64, NH / 64), dim3(256), 0, stream,
                       x, W_in, b_rec, rnn, T * NB, NH, NI);

    // sequential recurrence (persistent, tagged-word RMW sync, no fences)
    hipLaunchKernelGGL(k_rnn, dim3(256), dim3(512), 0, stream,
                       W_rec, noise, rnn, ex);

    // output = rnn @ W_out^T + b_out
    hipLaunchKernelGGL(k_gemm_nt_bias, dim3((T * NB) / 64, NO / 64), dim3(256), 0, stream,
                       rnn, W_out, b_out, out, T * NB, NO, NH);
}